// Round 6
// baseline (181.966 us; speedup 1.0000x reference)
//
#include <hip/hip_runtime.h>
#include <hip/hip_bf16.h>
#include <math.h>

#define PI_F 3.14159265358979323846f

// ---------------------------------------------------------------------------
// Kernel 1: build the fixed 64x64 complex unitary U (everything after the
// input RY layer). One block per INPUT basis state b (64 blocks x 64 lanes).
// Lane l holds amplitude of flat index l. Qubit q <-> bit (5-q).
// Store ROW-major by output index k: Umat[(k*64 + j)*2 + {0,1}] = {Re,Im} of
// U[k][j]. Row k = 512 contiguous bytes -> lane k loads its row as 32 float4.
// ---------------------------------------------------------------------------
__global__ __launch_bounds__(64) void build_u(const float* __restrict__ qw,
                                              float* __restrict__ Umat) {
    const int l = threadIdx.x;   // amplitude index k (0..63)
    const int b = blockIdx.x;    // input basis state j (0..63)

    float ar = (l == b) ? 1.0f : 0.0f;
    float ai = 0.0f;

    // Phase 2: for i: RX(qw[0][i], i) ; RZ(qw[1][i], i)
    #pragma unroll
    for (int i = 0; i < 6; ++i) {
        const int mask = 1 << (5 - i);
        float th = 0.5f * qw[0 * 6 + i];
        float c = cosf(th), sn = sinf(th);
        float pr = __shfl_xor(ar, mask);
        float pi = __shfl_xor(ai, mask);
        float nr = c * ar + sn * pi;
        float ni = c * ai - sn * pr;
        ar = nr; ai = ni;
        th = 0.5f * qw[1 * 6 + i];
        c = cosf(th); sn = sinf(th);
        float zn = (l & mask) ? 1.0f : -1.0f;
        nr = c * ar - zn * sn * ai;
        ni = c * ai + zn * sn * ar;
        ar = nr; ai = ni;
    }

    // CNOT ring: (0,1),(1,2),(2,3),(3,4),(4,5),(5,0)
    #pragma unroll
    for (int i = 0; i < 6; ++i) {
        const int ctrl = i, tgt = (i + 1) % 6;
        const int cm = 1 << (5 - ctrl), tm = 1 << (5 - tgt);
        float pr = __shfl_xor(ar, tm);
        float pi = __shfl_xor(ai, tm);
        bool take = (l & cm) != 0;
        ar = take ? pr : ar;
        ai = take ? pi : ai;
    }

    // Phase 4: for i: RY(qw[2][i], i) ; RZ(qw[3][i], i)
    #pragma unroll
    for (int i = 0; i < 6; ++i) {
        const int mask = 1 << (5 - i);
        float th = 0.5f * qw[2 * 6 + i];
        float c = cosf(th), sn = sinf(th);
        float pr = __shfl_xor(ar, mask);
        float pi = __shfl_xor(ai, mask);
        float sg = (l & mask) ? sn : -sn;
        float nr = c * ar + sg * pr;
        float ni = c * ai + sg * pi;
        ar = nr; ai = ni;
        th = 0.5f * qw[3 * 6 + i];
        c = cosf(th); sn = sinf(th);
        float zn = (l & mask) ? 1.0f : -1.0f;
        nr = c * ar - zn * sn * ai;
        ni = c * ai + zn * sn * ar;
        ar = nr; ai = ni;
    }

    // CNOTs (0,1),(2,3),(4,5)
    #pragma unroll
    for (int i = 0; i < 6; i += 2) {
        const int cm = 1 << (5 - i), tm = 1 << (5 - (i + 1));
        float pr = __shfl_xor(ar, tm);
        float pi = __shfl_xor(ai, tm);
        bool take = (l & cm) != 0;
        ar = take ? pr : ar;
        ai = take ? pi : ai;
    }

    // Phase 6: RX(qw[4][i], i)
    #pragma unroll
    for (int i = 0; i < 6; ++i) {
        const int mask = 1 << (5 - i);
        float th = 0.5f * qw[4 * 6 + i];
        float c = cosf(th), sn = sinf(th);
        float pr = __shfl_xor(ar, mask);
        float pi = __shfl_xor(ai, mask);
        float nr = c * ar + sn * pi;
        float ni = c * ai - sn * pr;
        ar = nr; ai = ni;
    }

    Umat[(l * 64 + b) * 2 + 0] = ar;   // row l (output k), col b (input j)
    Umat[(l * 64 + b) * 2 + 1] = ai;
}

// uniform-lane readlane -> SGPR float
__device__ __forceinline__ float readlane_f(float v, int srclane) {
    return __int_as_float(__builtin_amdgcn_readlane(__float_as_int(v), srclane));
}

// ---------------------------------------------------------------------------
// Kernel 2: wave-cooperative fused pipeline. ONE WAVE per block (64 threads),
// __launch_bounds__(64) -> VGPR cap 512, so the 128-VGPR U row CANNOT be a
// reason to spill. U row held in 32 NAMED float4 variables (no array, nothing
// the allocator can sink/rematerialize by index). Per sample t: lane t's
// hi/lo half-product tables are broadcast via v_readlane into SGPRs; lane k
// computes phi_k (144 FMA, zero memory traffic), p_k = |phi_k|^2; a 6-stage
// Walsh-Hadamard shfl_xor butterfly produces the 6 signed sums.
// ---------------------------------------------------------------------------
__global__ __launch_bounds__(64) void fused_main(
    const float* __restrict__ x,
    const float* __restrict__ W1, const float* __restrict__ b1,
    const float* __restrict__ W2, const float* __restrict__ b2,
    const float* __restrict__ W3, const float* __restrict__ b3,
    const float* __restrict__ W4, const float* __restrict__ b4,
    const float* __restrict__ W5, const float* __restrict__ b5,
    const float* __restrict__ Umat,
    float* __restrict__ out, int B)
{
    const int lane = threadIdx.x;            // 0..63 (one wave per block)
    const long sbase = (long)blockIdx.x * 64;
    const int  s_my  = (int)(sbase + lane);
    const int  s_ld  = (s_my < B) ? s_my : (B - 1);

    // ---- Layer 1: h1 = relu(x[s,:] @ W1 + b1)   (128 -> 32)
    float h1[32];
    #pragma unroll
    for (int o = 0; o < 32; ++o) h1[o] = b1[o];
    const float4* x4 = reinterpret_cast<const float4*>(x + (size_t)s_ld * 128);
    #pragma unroll 1
    for (int j4 = 0; j4 < 32; ++j4) {
        float4 xv = x4[j4];
        const float* w = W1 + j4 * 4 * 32;   // row-major (128,32)
        #pragma unroll
        for (int o = 0; o < 32; ++o) h1[o] = fmaf(xv.x, w[o], h1[o]);
        #pragma unroll
        for (int o = 0; o < 32; ++o) h1[o] = fmaf(xv.y, w[32 + o], h1[o]);
        #pragma unroll
        for (int o = 0; o < 32; ++o) h1[o] = fmaf(xv.z, w[64 + o], h1[o]);
        #pragma unroll
        for (int o = 0; o < 32; ++o) h1[o] = fmaf(xv.w, w[96 + o], h1[o]);
    }
    #pragma unroll
    for (int o = 0; o < 32; ++o) h1[o] = fmaxf(h1[o], 0.0f);

    // ---- Layer 2: h2 = relu(h1 @ W2 + b2)   (32 -> 16)
    float h2[16];
    #pragma unroll
    for (int o = 0; o < 16; ++o) h2[o] = b2[o];
    #pragma unroll
    for (int j = 0; j < 32; ++j) {
        #pragma unroll
        for (int o = 0; o < 16; ++o) h2[o] = fmaf(h1[j], W2[j * 16 + o], h2[o]);
    }
    #pragma unroll
    for (int o = 0; o < 16; ++o) h2[o] = fmaxf(h2[o], 0.0f);

    // ---- Layer 3: angles -> half-angle cos/sin per qubit (named scalars)
    float cq0, cq1, cq2, cq3, cq4, cq5, sq0, sq1, sq2, sq3, sq4, sq5;
    #define ANGLE(Q)                                                        \
        {                                                                   \
            float t = b3[Q];                                                \
            _Pragma("unroll")                                               \
            for (int j = 0; j < 16; ++j) t = fmaf(h2[j], W3[j * 6 + Q], t); \
            t = tanhf(t);                                                   \
            t = fminf(1.0f, fmaxf(-1.0f, t));                               \
            float half = t * (0.5f * PI_F);                                 \
            sq##Q = sinf(half);                                             \
            cq##Q = cosf(half);                                             \
        }
    ANGLE(0) ANGLE(1) ANGLE(2) ANGLE(3) ANGLE(4) ANGLE(5)
    #undef ANGLE

    // ---- half-product tables as NAMED scalars: psi[j] = hi[j>>3] * lo[j&7]
    // lo bits (b2,b1,b0) = (q3,q4,q5) sin-flags ; hi bits = (q0,q1,q2)
    float lo0 = cq3 * cq4 * cq5, lo1 = cq3 * cq4 * sq5;
    float lo2 = cq3 * sq4 * cq5, lo3 = cq3 * sq4 * sq5;
    float lo4 = sq3 * cq4 * cq5, lo5 = sq3 * cq4 * sq5;
    float lo6 = sq3 * sq4 * cq5, lo7 = sq3 * sq4 * sq5;
    float hi0 = cq0 * cq1 * cq2, hi1 = cq0 * cq1 * sq2;
    float hi2 = cq0 * sq1 * cq2, hi3 = cq0 * sq1 * sq2;
    float hi4 = sq0 * cq1 * cq2, hi5 = sq0 * cq1 * sq2;
    float hi6 = sq0 * sq1 * cq2, hi7 = sq0 * sq1 * sq2;

    // ---- this lane's U row (output index k = lane): 32 NAMED float4
    const float4* urow = reinterpret_cast<const float4*>(Umat + lane * 128);
    #define LOAD_U(I) float4 R##I = urow[I];
    LOAD_U(0)  LOAD_U(1)  LOAD_U(2)  LOAD_U(3)
    LOAD_U(4)  LOAD_U(5)  LOAD_U(6)  LOAD_U(7)
    LOAD_U(8)  LOAD_U(9)  LOAD_U(10) LOAD_U(11)
    LOAD_U(12) LOAD_U(13) LOAD_U(14) LOAD_U(15)
    LOAD_U(16) LOAD_U(17) LOAD_U(18) LOAD_U(19)
    LOAD_U(20) LOAD_U(21) LOAD_U(22) LOAD_U(23)
    LOAD_U(24) LOAD_U(25) LOAD_U(26) LOAD_U(27)
    LOAD_U(28) LOAD_U(29) LOAD_U(30) LOAD_U(31)
    #undef LOAD_U

    // ---- cooperative sample loop
    float q0 = 0.f, q1 = 0.f, q2 = 0.f, q3 = 0.f, q4 = 0.f, q5 = 0.f;

    // one jh-group: 8 complex FMA into (tr,ti), folded by bh into (pr,pim)
    #define GEMV_STEP(A, Bq, C, D, BH)                                  \
        {                                                               \
            float tr = A.x * bl0, ti = A.y * bl0;                       \
            tr = fmaf(A.z,  bl1, tr); ti = fmaf(A.w,  bl1, ti);         \
            tr = fmaf(Bq.x, bl2, tr); ti = fmaf(Bq.y, bl2, ti);         \
            tr = fmaf(Bq.z, bl3, tr); ti = fmaf(Bq.w, bl3, ti);         \
            tr = fmaf(C.x,  bl4, tr); ti = fmaf(C.y,  bl4, ti);         \
            tr = fmaf(C.z,  bl5, tr); ti = fmaf(C.w,  bl5, ti);         \
            tr = fmaf(D.x,  bl6, tr); ti = fmaf(D.y,  bl6, ti);         \
            tr = fmaf(D.z,  bl7, tr); ti = fmaf(D.w,  bl7, ti);         \
            pr  = fmaf(BH, tr, pr);                                     \
            pim = fmaf(BH, ti, pim);                                    \
        }

    #pragma unroll 1
    for (int t = 0; t < 64; ++t) {
        // broadcast sample t's tables into SGPRs
        float bl0 = readlane_f(lo0, t), bl1 = readlane_f(lo1, t);
        float bl2 = readlane_f(lo2, t), bl3 = readlane_f(lo3, t);
        float bl4 = readlane_f(lo4, t), bl5 = readlane_f(lo5, t);
        float bl6 = readlane_f(lo6, t), bl7 = readlane_f(lo7, t);
        float bh0 = readlane_f(hi0, t), bh1 = readlane_f(hi1, t);
        float bh2 = readlane_f(hi2, t), bh3 = readlane_f(hi3, t);
        float bh4 = readlane_f(hi4, t), bh5 = readlane_f(hi5, t);
        float bh6 = readlane_f(hi6, t), bh7 = readlane_f(hi7, t);

        float pr = 0.f, pim = 0.f;
        GEMV_STEP(R0,  R1,  R2,  R3,  bh0)
        GEMV_STEP(R4,  R5,  R6,  R7,  bh1)
        GEMV_STEP(R8,  R9,  R10, R11, bh2)
        GEMV_STEP(R12, R13, R14, R15, bh3)
        GEMV_STEP(R16, R17, R18, R19, bh4)
        GEMV_STEP(R20, R21, R22, R23, bh5)
        GEMV_STEP(R24, R25, R26, R27, bh6)
        GEMV_STEP(R28, R29, R30, R31, bh7)

        float p = fmaf(pr, pr, pim * pim);   // |phi_k|^2 at lane k

        // Walsh-Hadamard butterfly: lane r ends with sum_k (-1)^{popc(r&k)} p_k
        float v = p;
        #pragma unroll
        for (int st = 0; st < 6; ++st) {
            const int m = 1 << st;
            float prt = __shfl_xor(v, m);
            v = (lane & m) ? (prt - v) : (prt + v);
        }

        // qv[q] = WHT coefficient at r = 1<<(5-q); deliver to owner lane t
        float g0 = readlane_f(v, 32);
        float g1 = readlane_f(v, 16);
        float g2 = readlane_f(v, 8);
        float g3 = readlane_f(v, 4);
        float g4 = readlane_f(v, 2);
        float g5 = readlane_f(v, 1);
        if (lane == t) { q0 = g0; q1 = g1; q2 = g2; q3 = g3; q4 = g4; q5 = g5; }
    }
    #undef GEMV_STEP

    if (s_my >= B) return;

    // ---- Layer 4: h4 = relu(q_out @ W4 + b4)   (6 -> 16)
    float qv[6] = {q0, q1, q2, q3, q4, q5};
    float h4[16];
    #pragma unroll
    for (int o = 0; o < 16; ++o) h4[o] = b4[o];
    #pragma unroll
    for (int q = 0; q < 6; ++q) {
        #pragma unroll
        for (int o = 0; o < 16; ++o) h4[o] = fmaf(qv[q], W4[q * 16 + o], h4[o]);
    }
    #pragma unroll
    for (int o = 0; o < 16; ++o) h4[o] = fmaxf(h4[o], 0.0f);

    // ---- Layer 5: out = h4 @ W5 + b5   (16 -> 20)
    float o5[20];
    #pragma unroll
    for (int o = 0; o < 20; ++o) {
        float t = b5[o];
        #pragma unroll
        for (int j = 0; j < 16; ++j) t = fmaf(h4[j], W5[j * 20 + o], t);
        o5[o] = t;
    }
    float4* outv = reinterpret_cast<float4*>(out + (size_t)s_my * 20);
    #pragma unroll
    for (int i = 0; i < 5; ++i)
        outv[i] = make_float4(o5[4 * i], o5[4 * i + 1], o5[4 * i + 2], o5[4 * i + 3]);
}

// ---------------------------------------------------------------------------
extern "C" void kernel_launch(void* const* d_in, const int* in_sizes, int n_in,
                              void* d_out, int out_size, void* d_ws, size_t ws_size,
                              hipStream_t stream) {
    const float* x  = (const float*)d_in[0];
    const float* W1 = (const float*)d_in[1];
    const float* b1 = (const float*)d_in[2];
    const float* W2 = (const float*)d_in[3];
    const float* b2 = (const float*)d_in[4];
    const float* W3 = (const float*)d_in[5];
    const float* b3 = (const float*)d_in[6];
    const float* qw = (const float*)d_in[7];
    const float* W4 = (const float*)d_in[8];
    const float* b4 = (const float*)d_in[9];
    const float* W5 = (const float*)d_in[10];
    const float* b5 = (const float*)d_in[11];
    float* out = (float*)d_out;
    float* Umat = (float*)d_ws;   // 64*64*2 floats = 32 KB

    const int B = in_sizes[0] / 128;

    build_u<<<64, 64, 0, stream>>>(qw, Umat);
    fused_main<<<(B + 63) / 64, 64, 0, stream>>>(
        x, W1, b1, W2, b2, W3, b3, W4, b4, W5, b5, Umat, out, B);
}